// Round 10
// baseline (371.534 us; speedup 1.0000x reference)
//
#include <hip/hip_runtime.h>

// DiffeomorphicLearnerTorch, R15 = R14 (366.8us, verified) + cross-tile
// operand prefetch rotation (T14 issue-early, zero reg cost).
// R14 post-mortem: setprio WIN matched prediction (381->366.8). Remaining
// k_flash accounting: MFMA issue ~2k cyc/tile/SIMD vs ~11k wall; the one
// structural exposed window left: bv (producer, 16 Zf frags, L2 ~300cyc)
// and bw (consumer, 8 ATf frags, L3 ~500-900cyc) are issued at tile top and
// consumed immediately -> full round-trip serialized into EVERY tile.
// R15 rotates the hoists: load tile n+1's bv/bw right after tile n's MFMA
// cluster consumes the old values — SAME registers (WAR via scoreboard,
// proven benign in R13's rolling window), so VGPR peak and 4 waves/SIMD
// occupancy are unchanged. Loads overlap exp/pack tail + ds_writes +
// barrier + next tile's LDS reads. Sa/Sb chain split deliberately NOT
// applied: +16 VGPR vs the 128 cap (launch_bounds(512,4)) = spill risk.
// Math identical to R6/R14 (verified, absmax 0.015625).
// Per step: Z += DT*(Z@Aaff^T + b + [ei*ej*exp(2*C1*Z@Z^T)]@A_t)
// Frag-linear layouts (verified R4/R5):
//   Zf  [128 jblk][16 ks][64 lane]x8 bf16
//   ATf [t][8 dblk][256 jb][64 lane]x8 bf16

#define N_PTS 4096
#define DIM   256
#define DT_C  0.125f
#define C1    (1.0f/512.0f)

typedef __bf16 bf16x8 __attribute__((ext_vector_type(8)));
typedef float  f32x16 __attribute__((ext_vector_type(16)));
typedef float  f32x4v __attribute__((ext_vector_type(4)));
typedef unsigned int   u32x4 __attribute__((ext_vector_type(4)));
typedef unsigned short u16x8 __attribute__((ext_vector_type(8)));

__device__ __forceinline__ unsigned short f2bf(float f) {
  unsigned int u = __builtin_bit_cast(unsigned int, f);
  u += 0x7fffu + ((u >> 16) & 1u);          // RNE
  return (unsigned short)(u >> 16);
}
__device__ __forceinline__ float bf2f(unsigned short s) {
  unsigned int u = ((unsigned int)s) << 16;
  return __builtin_bit_cast(float, u);
}

// ---- ATf: A[t][4096][256] f32 -> frag-linear bf16 B-operand tiles ----
__global__ __launch_bounds__(256) void k_prep(const float* __restrict__ A,
                                              unsigned short* __restrict__ ATf) {
  __shared__ float sT[64][36];
  const int jgrp = blockIdx.x, ds = blockIdx.y, t = blockIdx.z;
  const int tid = threadIdx.x;
  const float* Ab = A + (size_t)t * N_PTS * DIM;
  {
    const int j_l = tid >> 2, dq = tid & 3;
    const float* src = Ab + (size_t)(jgrp * 64 + j_l) * DIM + ds * 32 + dq * 8;
    f32x4v v0 = *(const f32x4v*)src, v1 = *(const f32x4v*)(src + 4);
    *(f32x4v*)&sT[j_l][dq * 8] = v0;
    *(f32x4v*)&sT[j_l][dq * 8 + 4] = v1;
  }
  __syncthreads();
  const int jb_l = tid >> 6, l = tid & 63, l31 = l & 31, lhi = l >> 5;
  u16x8 o;
#pragma unroll
  for (int e = 0; e < 8; ++e) o[e] = f2bf(sT[jb_l * 16 + lhi * 8 + e][l31]);
  unsigned short* dst = ATf + (size_t)t * (8 * 256 * 64 * 8)
                      + ((size_t)(ds * 256 + jgrp * 4 + jb_l) * 64 + l) * 8;
  *(u16x8*)dst = o;
}

// ---- init: X -> Zf frags + erow ----
__global__ __launch_bounds__(256) void k_init(const float* __restrict__ X,
                                              unsigned short* __restrict__ Zf,
                                              float* __restrict__ erow) {
  const int tid = threadIdx.x;
  const int r = blockIdx.x * 8 + (tid >> 5), o = tid & 31;
  const size_t base = (size_t)r * DIM + o * 8;
  f32x4v z0 = *(const f32x4v*)(X + base), z1 = *(const f32x4v*)(X + base + 4);
  u16x8 zb; float s = 0.f;
#pragma unroll
  for (int i = 0; i < 4; ++i) { zb[i] = f2bf(z0[i]); zb[4 + i] = f2bf(z1[i]);
                                s += z0[i] * z0[i] + z1[i] * z1[i]; }
  *(u16x8*)(Zf + ((size_t)((r >> 5) * 16 + (o >> 1)) * 64 + (o & 1) * 32 + (r & 31)) * 8) = zb;
#pragma unroll
  for (int d = 16; d > 0; d >>= 1) s += __shfl_down(s, d, 32);
  if (o == 0) erow[r] = __expf(-s * C1);
}

// ---- fused flash (R6 structure + T5 setprio + T14 prefetch rotation) ----
// grid (8 chunks, 64 i-tiles of 64 rows), 512 thr = 8 waves, 2 blocks/CU.
// waves 0-3 producer (ip=wid>>1, jh=wid&1): S = Zi(32) @ Zj(32)^T;
//   af from sZi (LDS), bv x16 from global, ROTATED (n+1 issued post-S-chain).
// waves 4-7 consumer cd: O(64i x 64d) += P @ A_t; bw x8 from global, ROTATED;
//   + affine slice ksg=chunk*2+{0,1} (a-frags from sZi).
__global__ __launch_bounds__(512, 4) void k_flash(
    const unsigned short* __restrict__ Zf, const float* __restrict__ erow,
    const unsigned short* __restrict__ ATf_t,
    const float* __restrict__ Aaff_t,
    unsigned short* __restrict__ Opart) {
  __shared__ __align__(16) unsigned short sZi[64 * 256];   // 32KB frag-linear
  __shared__ __align__(16) unsigned short sP[2][64 * 64];  // 2 x 8KB swizzled

  const int tid = threadIdx.x, lane = tid & 63, wid = tid >> 6;
  const int l31 = lane & 31, lhi = lane >> 5;
  const int chunk = blockIdx.x;
  const int i0 = blockIdx.y * 64;
  const int ib = i0 >> 5;

  // stage sZi: 32KB contiguous slice of Zf (frag-linear already)
  {
    const unsigned short* src = Zf + (size_t)ib * 8192;
#pragma unroll
    for (int p = 0; p < 4; ++p)
      *(u32x4*)(sZi + (size_t)(p * 512 + tid) * 8) =
          *(const u32x4*)(src + (size_t)(p * 512 + tid) * 8);
  }
  __syncthreads();

  if (wid < 4) {
    // ================= producer =================
    const int ip = wid >> 1, jh = wid & 1;
    float eI[16];
#pragma unroll
    for (int c = 0; c < 16; ++c)
      eI[c] = erow[i0 + ip * 32 + 4 * lhi + (c & 3) + 8 * (c >> 2)];

    // tile-0 bv hoist (subsequent tiles rotated into the loop tail)
    u32x4 bv[16];
    {
      const unsigned short* bp =
          Zf + ((size_t)(chunk * 16 + jh) * 16 * 64 + lane) * 8;
#pragma unroll
      for (int ks = 0; ks < 16; ++ks) bv[ks] = *(const u32x4*)(bp + ks * 512);
    }

    for (int n = 0; n < 8; ++n) {
      f32x16 S;
#pragma unroll
      for (int i = 0; i < 16; ++i) S[i] = 0.f;
      __builtin_amdgcn_s_setprio(1);
#pragma unroll
      for (int ks = 0; ks < 16; ++ks) {
        bf16x8 af = *(const bf16x8*)(sZi + ((size_t)(ip * 16 + ks) * 64 + lane) * 8);
        S = __builtin_amdgcn_mfma_f32_32x32x16_bf16(af, __builtin_bit_cast(bf16x8, bv[ks]), S, 0, 0, 0);
      }
      __builtin_amdgcn_s_setprio(0);
      // rotate: issue tile n+1's bv now (same regs, WAR-safe); the L2
      // round-trip hides under the exp/pack tail + ds_writes + barrier.
      if (n < 7) {
        const unsigned short* bp =
            Zf + ((size_t)(chunk * 16 + (n + 1) * 2 + jh) * 16 * 64 + lane) * 8;
#pragma unroll
        for (int ks = 0; ks < 16; ++ks) bv[ks] = *(const u32x4*)(bp + ks * 512);
      }
      const float ej = erow[chunk * 512 + n * 64 + jh * 32 + l31];
      unsigned short* pb = sP[n & 1];
      const int blk = jh * 4 + (l31 >> 3), cl = l31 & 7;
#pragma unroll
      for (int c = 0; c < 16; ++c) {
        const int row = ip * 32 + 4 * lhi + (c & 3) + 8 * (c >> 2);
        pb[row * 64 + ((blk ^ (row & 7)) * 8) + cl] =
            f2bf(eI[c] * ej * __expf(2.f * C1 * S[c]));
      }
      __syncthreads();
    }
    __syncthreads();   // match consumer's 9th barrier
  } else {
    // ================= consumer =================
    const int cd = wid - 4;
    f32x16 O[2][2];
#pragma unroll
    for (int rs = 0; rs < 2; ++rs)
#pragma unroll
      for (int ct = 0; ct < 2; ++ct)
#pragma unroll
        for (int i = 0; i < 16; ++i) O[rs][ct][i] = 0.f;

    // affine slice (unscaled): ksg = chunk*2 + {0,1}; a-frags from sZi
#pragma unroll
    for (int q = 0; q < 2; ++q) {
      const int ksg = chunk * 2 + q;
      bf16x8 a[2];
#pragma unroll
      for (int rs = 0; rs < 2; ++rs)
        a[rs] = *(const bf16x8*)(sZi + ((size_t)(rs * 16 + ksg) * 64 + lane) * 8);
#pragma unroll
      for (int ct = 0; ct < 2; ++ct) {
        const int d = cd * 64 + ct * 32 + l31;
        const float* bp = Aaff_t + (size_t)d * DIM + ksg * 16 + lhi * 8;
        f32x4v f0 = *(const f32x4v*)bp, f1 = *(const f32x4v*)(bp + 4);
        u16x8 tb;
#pragma unroll
        for (int i = 0; i < 4; ++i) { tb[i] = f2bf(f0[i]); tb[4 + i] = f2bf(f1[i]); }
        bf16x8 bv = __builtin_bit_cast(bf16x8, tb);
#pragma unroll
        for (int rs = 0; rs < 2; ++rs)
          O[rs][ct] = __builtin_amdgcn_mfma_f32_32x32x16_bf16(a[rs], bv, O[rs][ct], 0, 0, 0);
      }
    }

    // tile-0 bw hoist BEFORE barrier 1: the L3 round-trip hides under the
    // producer's tile-0 S-chain (subsequent tiles rotated into loop tail).
    u32x4 bw[8];
#pragma unroll
    for (int ks = 0; ks < 4; ++ks)
#pragma unroll
      for (int ct = 0; ct < 2; ++ct)
        bw[ks * 2 + ct] = *(const u32x4*)(ATf_t +
            ((size_t)((cd * 2 + ct) * 256 + chunk * 32 + ks) * 64 + lane) * 8);
    __syncthreads();   // barrier 1 (producer finished tile 0)

    for (int n = 1; n <= 8; ++n) {
      const int m = n - 1;
      const unsigned short* pb = sP[m & 1];
#pragma unroll
      for (int ks = 0; ks < 4; ++ks) {
        bf16x8 a[2];
        const int blk = ks * 2 + lhi;
#pragma unroll
        for (int rs = 0; rs < 2; ++rs) {
          const int row = rs * 32 + l31;
          a[rs] = *(const bf16x8*)&pb[row * 64 + ((blk ^ (row & 7)) * 8)];
        }
        __builtin_amdgcn_s_setprio(1);
#pragma unroll
        for (int rs = 0; rs < 2; ++rs)
#pragma unroll
          for (int ct = 0; ct < 2; ++ct)
            O[rs][ct] = __builtin_amdgcn_mfma_f32_32x32x16_bf16(
                a[rs], __builtin_bit_cast(bf16x8, bw[ks * 2 + ct]), O[rs][ct], 0, 0, 0);
        __builtin_amdgcn_s_setprio(0);
      }
      // rotate: issue tile m+1's bw now (same regs, WAR-safe); hides under
      // the barrier wait + next tile's LDS reads.
      if (n < 8) {
#pragma unroll
        for (int ks = 0; ks < 4; ++ks)
#pragma unroll
          for (int ct = 0; ct < 2; ++ct)
            bw[ks * 2 + ct] = *(const u32x4*)(ATf_t +
                ((size_t)((cd * 2 + ct) * 256 + chunk * 32 + (m + 1) * 4 + ks) * 64 + lane) * 8);
      }
      __syncthreads();
    }

    // epilogue -> Opart[chunk] bf16 (P already carries ei*ej)
    unsigned short* ob = Opart + (size_t)chunk * N_PTS * DIM + (size_t)cd * 64 + l31;
#pragma unroll
    for (int rs = 0; rs < 2; ++rs)
#pragma unroll
      for (int c = 0; c < 16; ++c) {
        const int row = i0 + rs * 32 + 4 * lhi + (c & 3) + 8 * (c >> 2);
        ob[(size_t)row * DIM]      = f2bf(O[rs][0][c]);
        ob[(size_t)row * DIM + 32] = f2bf(O[rs][1][c]);
      }
  }
}

// ---- update: Z += DT*(sum partials + baff); emit Zf frags + erow ----
__global__ __launch_bounds__(256) void k_update(const float* __restrict__ Zin,
                                                const unsigned short* __restrict__ Opart,
                                                const float* __restrict__ baff_t,
                                                float* __restrict__ Zout,
                                                unsigned short* __restrict__ Zf,
                                                float* __restrict__ erow) {
  const int tid = threadIdx.x;
  const int r = blockIdx.x * 8 + (tid >> 5), o = tid & 31;
  const size_t base = (size_t)r * DIM + o * 8;
  f32x4v z0 = *(const f32x4v*)(Zin + base), z1 = *(const f32x4v*)(Zin + base + 4);
  f32x4v s0 = *(const f32x4v*)(baff_t + o * 8), s1 = *(const f32x4v*)(baff_t + o * 8 + 4);
#pragma unroll
  for (int c = 0; c < 8; ++c) {
    u16x8 p = *(const u16x8*)(Opart + (size_t)c * N_PTS * DIM + base);
#pragma unroll
    for (int i = 0; i < 4; ++i) { s0[i] += bf2f(p[i]); s1[i] += bf2f(p[4 + i]); }
  }
  u16x8 zb; float sv = 0.f;
#pragma unroll
  for (int i = 0; i < 4; ++i) {
    z0[i] += DT_C * s0[i]; z1[i] += DT_C * s1[i];
    zb[i] = f2bf(z0[i]); zb[4 + i] = f2bf(z1[i]);
    sv += z0[i] * z0[i] + z1[i] * z1[i];
  }
  *(f32x4v*)(Zout + base) = z0;
  *(f32x4v*)(Zout + base + 4) = z1;
  *(u16x8*)(Zf + ((size_t)((r >> 5) * 16 + (o >> 1)) * 64 + (o & 1) * 32 + (r & 31)) * 8) = zb;
#pragma unroll
  for (int d = 16; d > 0; d >>= 1) sv += __shfl_down(sv, d, 32);
  if (o == 0) erow[r] = __expf(-sv * C1);
}

extern "C" void kernel_launch(void* const* d_in, const int* in_sizes, int n_in,
                              void* d_out, int out_size, void* d_ws, size_t ws_size,
                              hipStream_t stream) {
  const float* X    = (const float*)d_in[0];
  const float* A    = (const float*)d_in[1];
  const float* Aaff = (const float*)d_in[2];
  const float* baff = (const float*)d_in[3];
  float* out = (float*)d_out;

  char* w = (char*)d_ws;
  size_t off = 0;
  unsigned short* ATf = (unsigned short*)(w + off); off += (size_t)8 * 8 * 256 * 64 * 8 * 2; // 16 MiB
  unsigned short* Zf  = (unsigned short*)(w + off); off += (size_t)N_PTS * DIM * 2;          // 2 MiB
  float* erow = (float*)(w + off); off += (size_t)N_PTS * 4;
  float* Zf32 = (float*)(w + off); off += (size_t)N_PTS * DIM * 4;                           // 4 MiB
  unsigned short* Opart = (unsigned short*)(w + off); off += (size_t)8 * N_PTS * DIM * 2;    // 16 MiB
  (void)ws_size; (void)in_sizes; (void)n_in; (void)out_size;

  k_prep<<<dim3(64, 8, 8), 256, 0, stream>>>(A, ATf);
  k_init<<<512, 256, 0, stream>>>(X, Zf, erow);

  const float* zin = X;
  for (int t = 0; t < 8; ++t) {
    float* zout = (t == 7) ? out : Zf32;  // in-place safe after t=0
    k_flash<<<dim3(8, 64), 512, 0, stream>>>(
        Zf, erow, ATf + (size_t)t * (8 * 256 * 64 * 8), Aaff + (size_t)t * DIM * DIM, Opart);
    k_update<<<512, 256, 0, stream>>>(zin, Opart, baff + (size_t)t * DIM, zout, Zf, erow);
    zin = zout;
  }
}

// Round 11
// 366.573 us; speedup vs baseline: 1.0135x; 1.0135x over previous
//
#include <hip/hip_runtime.h>

// DiffeomorphicLearnerTorch, R16 = R14 (366.8us session best) + half-rate
// barriers via sP[4]. R15 post-mortem: prefetch rotation REGRESSED (371.5)
// — in the role-split structure a wave's operand-load latency is already
// hidden by the other ~3 waves/SIMD; rotation only stretched live ranges.
// Reverted to R14 load placement. Remaining structural coupling: 10
// __syncthreads per k_flash (1/tile), each a full vmcnt/lgkm drain +
// 8-wave re-convoy charging the producer/consumer phase imbalance to the
// wall. R16: sP 2->4 buffers (LDS 48->64KB, still 2 blocks/CU @ (512,4));
// producer writes tiles {2p,2p+1} per phase, ONE barrier per phase;
// consumer reads both after it. Race-checked: phase-p writes slots
// (2p)%4,(2p+1)%4; consumer reads phase p-1's slots (disjoint); slot reuse
// at p+2 separated from consumer reads by barrier p+1. Barriers 10 -> 5.
// Both roles: 1 stage-B + 4 phase-Bs (counts match). Regs unchanged.
// Math identical to R6/R14 (verified, absmax 0.015625).
// Per step: Z += DT*(Z@Aaff^T + b + [ei*ej*exp(2*C1*Z@Z^T)]@A_t)
// Frag-linear layouts (verified R4/R5):
//   Zf  [128 jblk][16 ks][64 lane]x8 bf16
//   ATf [t][8 dblk][256 jb][64 lane]x8 bf16

#define N_PTS 4096
#define DIM   256
#define DT_C  0.125f
#define C1    (1.0f/512.0f)

typedef __bf16 bf16x8 __attribute__((ext_vector_type(8)));
typedef float  f32x16 __attribute__((ext_vector_type(16)));
typedef float  f32x4v __attribute__((ext_vector_type(4)));
typedef unsigned int   u32x4 __attribute__((ext_vector_type(4)));
typedef unsigned short u16x8 __attribute__((ext_vector_type(8)));

__device__ __forceinline__ unsigned short f2bf(float f) {
  unsigned int u = __builtin_bit_cast(unsigned int, f);
  u += 0x7fffu + ((u >> 16) & 1u);          // RNE
  return (unsigned short)(u >> 16);
}
__device__ __forceinline__ float bf2f(unsigned short s) {
  unsigned int u = ((unsigned int)s) << 16;
  return __builtin_bit_cast(float, u);
}

// ---- ATf: A[t][4096][256] f32 -> frag-linear bf16 B-operand tiles ----
__global__ __launch_bounds__(256) void k_prep(const float* __restrict__ A,
                                              unsigned short* __restrict__ ATf) {
  __shared__ float sT[64][36];
  const int jgrp = blockIdx.x, ds = blockIdx.y, t = blockIdx.z;
  const int tid = threadIdx.x;
  const float* Ab = A + (size_t)t * N_PTS * DIM;
  {
    const int j_l = tid >> 2, dq = tid & 3;
    const float* src = Ab + (size_t)(jgrp * 64 + j_l) * DIM + ds * 32 + dq * 8;
    f32x4v v0 = *(const f32x4v*)src, v1 = *(const f32x4v*)(src + 4);
    *(f32x4v*)&sT[j_l][dq * 8] = v0;
    *(f32x4v*)&sT[j_l][dq * 8 + 4] = v1;
  }
  __syncthreads();
  const int jb_l = tid >> 6, l = tid & 63, l31 = l & 31, lhi = l >> 5;
  u16x8 o;
#pragma unroll
  for (int e = 0; e < 8; ++e) o[e] = f2bf(sT[jb_l * 16 + lhi * 8 + e][l31]);
  unsigned short* dst = ATf + (size_t)t * (8 * 256 * 64 * 8)
                      + ((size_t)(ds * 256 + jgrp * 4 + jb_l) * 64 + l) * 8;
  *(u16x8*)dst = o;
}

// ---- init: X -> Zf frags + erow ----
__global__ __launch_bounds__(256) void k_init(const float* __restrict__ X,
                                              unsigned short* __restrict__ Zf,
                                              float* __restrict__ erow) {
  const int tid = threadIdx.x;
  const int r = blockIdx.x * 8 + (tid >> 5), o = tid & 31;
  const size_t base = (size_t)r * DIM + o * 8;
  f32x4v z0 = *(const f32x4v*)(X + base), z1 = *(const f32x4v*)(X + base + 4);
  u16x8 zb; float s = 0.f;
#pragma unroll
  for (int i = 0; i < 4; ++i) { zb[i] = f2bf(z0[i]); zb[4 + i] = f2bf(z1[i]);
                                s += z0[i] * z0[i] + z1[i] * z1[i]; }
  *(u16x8*)(Zf + ((size_t)((r >> 5) * 16 + (o >> 1)) * 64 + (o & 1) * 32 + (r & 31)) * 8) = zb;
#pragma unroll
  for (int d = 16; d > 0; d >>= 1) s += __shfl_down(s, d, 32);
  if (o == 0) erow[r] = __expf(-s * C1);
}

// ---- fused flash (R6 structure + T5 setprio + 2-tile phases) ----
// grid (8 chunks, 64 i-tiles of 64 rows), 512 thr = 8 waves, 2 blocks/CU.
// waves 0-3 producer (ip=wid>>1, jh=wid&1): S = Zi(32) @ Zj(32)^T;
//   af from sZi (LDS), bv x16 from global (R14 placement). P -> sP[n&3].
// waves 4-7 consumer cd: O(64i x 64d) += P @ A_t; bw x8 per tile;
//   + affine slice ksg=chunk*2+{0,1} (a-frags from sZi).
// Phases of 2 tiles; ONE barrier per phase (5 total incl. staging).
__global__ __launch_bounds__(512, 4) void k_flash(
    const unsigned short* __restrict__ Zf, const float* __restrict__ erow,
    const unsigned short* __restrict__ ATf_t,
    const float* __restrict__ Aaff_t,
    unsigned short* __restrict__ Opart) {
  __shared__ __align__(16) unsigned short sZi[64 * 256];   // 32KB frag-linear
  __shared__ __align__(16) unsigned short sP[4][64 * 64];  // 4 x 8KB swizzled

  const int tid = threadIdx.x, lane = tid & 63, wid = tid >> 6;
  const int l31 = lane & 31, lhi = lane >> 5;
  const int chunk = blockIdx.x;
  const int i0 = blockIdx.y * 64;
  const int ib = i0 >> 5;

  // stage sZi: 32KB contiguous slice of Zf (frag-linear already)
  {
    const unsigned short* src = Zf + (size_t)ib * 8192;
#pragma unroll
    for (int p = 0; p < 4; ++p)
      *(u32x4*)(sZi + (size_t)(p * 512 + tid) * 8) =
          *(const u32x4*)(src + (size_t)(p * 512 + tid) * 8);
  }
  __syncthreads();

  if (wid < 4) {
    // ================= producer =================
    const int ip = wid >> 1, jh = wid & 1;
    float eI[16];
#pragma unroll
    for (int c = 0; c < 16; ++c)
      eI[c] = erow[i0 + ip * 32 + 4 * lhi + (c & 3) + 8 * (c >> 2)];

    for (int ph = 0; ph < 4; ++ph) {
#pragma unroll
      for (int h = 0; h < 2; ++h) {
        const int n = ph * 2 + h;
        // hoist the 16 b-frags for this tile (R14 placement)
        u32x4 bv[16];
        {
          const unsigned short* bp =
              Zf + ((size_t)(chunk * 16 + n * 2 + jh) * 16 * 64 + lane) * 8;
#pragma unroll
          for (int ks = 0; ks < 16; ++ks) bv[ks] = *(const u32x4*)(bp + ks * 512);
        }
        f32x16 S;
#pragma unroll
        for (int i = 0; i < 16; ++i) S[i] = 0.f;
        __builtin_amdgcn_s_setprio(1);
#pragma unroll
        for (int ks = 0; ks < 16; ++ks) {
          bf16x8 af = *(const bf16x8*)(sZi + ((size_t)(ip * 16 + ks) * 64 + lane) * 8);
          S = __builtin_amdgcn_mfma_f32_32x32x16_bf16(af, __builtin_bit_cast(bf16x8, bv[ks]), S, 0, 0, 0);
        }
        __builtin_amdgcn_s_setprio(0);
        const float ej = erow[chunk * 512 + n * 64 + jh * 32 + l31];
        unsigned short* pb = sP[n & 3];
        const int blk = jh * 4 + (l31 >> 3), cl = l31 & 7;
#pragma unroll
        for (int c = 0; c < 16; ++c) {
          const int row = ip * 32 + 4 * lhi + (c & 3) + 8 * (c >> 2);
          pb[row * 64 + ((blk ^ (row & 7)) * 8) + cl] =
              f2bf(eI[c] * ej * __expf(2.f * C1 * S[c]));
        }
      }
      __syncthreads();   // publish tiles 2p, 2p+1
    }
  } else {
    // ================= consumer =================
    const int cd = wid - 4;
    f32x16 O[2][2];
#pragma unroll
    for (int rs = 0; rs < 2; ++rs)
#pragma unroll
      for (int ct = 0; ct < 2; ++ct)
#pragma unroll
        for (int i = 0; i < 16; ++i) O[rs][ct][i] = 0.f;

    // affine slice (unscaled): ksg = chunk*2 + {0,1}; a-frags from sZi
#pragma unroll
    for (int q = 0; q < 2; ++q) {
      const int ksg = chunk * 2 + q;
      bf16x8 a[2];
#pragma unroll
      for (int rs = 0; rs < 2; ++rs)
        a[rs] = *(const bf16x8*)(sZi + ((size_t)(rs * 16 + ksg) * 64 + lane) * 8);
#pragma unroll
      for (int ct = 0; ct < 2; ++ct) {
        const int d = cd * 64 + ct * 32 + l31;
        const float* bp = Aaff_t + (size_t)d * DIM + ksg * 16 + lhi * 8;
        f32x4v f0 = *(const f32x4v*)bp, f1 = *(const f32x4v*)(bp + 4);
        u16x8 tb;
#pragma unroll
        for (int i = 0; i < 4; ++i) { tb[i] = f2bf(f0[i]); tb[4 + i] = f2bf(f1[i]); }
        bf16x8 bv = __builtin_bit_cast(bf16x8, tb);
#pragma unroll
        for (int rs = 0; rs < 2; ++rs)
          O[rs][ct] = __builtin_amdgcn_mfma_f32_32x32x16_bf16(a[rs], bv, O[rs][ct], 0, 0, 0);
      }
    }

    for (int ph = 0; ph < 4; ++ph) {
      __syncthreads();   // tiles 2p, 2p+1 published
#pragma unroll
      for (int h = 0; h < 2; ++h) {
        const int m = ph * 2 + h;
        // hoist the 8 ATf b-frags for this tile (R14 placement)
        u32x4 bw[8];
#pragma unroll
        for (int ks = 0; ks < 4; ++ks)
#pragma unroll
          for (int ct = 0; ct < 2; ++ct)
            bw[ks * 2 + ct] = *(const u32x4*)(ATf_t +
                ((size_t)((cd * 2 + ct) * 256 + chunk * 32 + m * 4 + ks) * 64 + lane) * 8);
        const unsigned short* pb = sP[m & 3];
#pragma unroll
        for (int ks = 0; ks < 4; ++ks) {
          bf16x8 a[2];
          const int blk = ks * 2 + lhi;
#pragma unroll
          for (int rs = 0; rs < 2; ++rs) {
            const int row = rs * 32 + l31;
            a[rs] = *(const bf16x8*)&pb[row * 64 + ((blk ^ (row & 7)) * 8)];
          }
          __builtin_amdgcn_s_setprio(1);
#pragma unroll
          for (int rs = 0; rs < 2; ++rs)
#pragma unroll
            for (int ct = 0; ct < 2; ++ct)
              O[rs][ct] = __builtin_amdgcn_mfma_f32_32x32x16_bf16(
                  a[rs], __builtin_bit_cast(bf16x8, bw[ks * 2 + ct]), O[rs][ct], 0, 0, 0);
          __builtin_amdgcn_s_setprio(0);
        }
      }
    }

    // epilogue -> Opart[chunk] bf16 (P already carries ei*ej)
    unsigned short* ob = Opart + (size_t)chunk * N_PTS * DIM + (size_t)cd * 64 + l31;
#pragma unroll
    for (int rs = 0; rs < 2; ++rs)
#pragma unroll
      for (int c = 0; c < 16; ++c) {
        const int row = i0 + rs * 32 + 4 * lhi + (c & 3) + 8 * (c >> 2);
        ob[(size_t)row * DIM]      = f2bf(O[rs][0][c]);
        ob[(size_t)row * DIM + 32] = f2bf(O[rs][1][c]);
      }
  }
}

// ---- update: Z += DT*(sum partials + baff); emit Zf frags + erow ----
__global__ __launch_bounds__(256) void k_update(const float* __restrict__ Zin,
                                                const unsigned short* __restrict__ Opart,
                                                const float* __restrict__ baff_t,
                                                float* __restrict__ Zout,
                                                unsigned short* __restrict__ Zf,
                                                float* __restrict__ erow) {
  const int tid = threadIdx.x;
  const int r = blockIdx.x * 8 + (tid >> 5), o = tid & 31;
  const size_t base = (size_t)r * DIM + o * 8;
  f32x4v z0 = *(const f32x4v*)(Zin + base), z1 = *(const f32x4v*)(Zin + base + 4);
  f32x4v s0 = *(const f32x4v*)(baff_t + o * 8), s1 = *(const f32x4v*)(baff_t + o * 8 + 4);
#pragma unroll
  for (int c = 0; c < 8; ++c) {
    u16x8 p = *(const u16x8*)(Opart + (size_t)c * N_PTS * DIM + base);
#pragma unroll
    for (int i = 0; i < 4; ++i) { s0[i] += bf2f(p[i]); s1[i] += bf2f(p[4 + i]); }
  }
  u16x8 zb; float sv = 0.f;
#pragma unroll
  for (int i = 0; i < 4; ++i) {
    z0[i] += DT_C * s0[i]; z1[i] += DT_C * s1[i];
    zb[i] = f2bf(z0[i]); zb[4 + i] = f2bf(z1[i]);
    sv += z0[i] * z0[i] + z1[i] * z1[i];
  }
  *(f32x4v*)(Zout + base) = z0;
  *(f32x4v*)(Zout + base + 4) = z1;
  *(u16x8*)(Zf + ((size_t)((r >> 5) * 16 + (o >> 1)) * 64 + (o & 1) * 32 + (r & 31)) * 8) = zb;
#pragma unroll
  for (int d = 16; d > 0; d >>= 1) sv += __shfl_down(sv, d, 32);
  if (o == 0) erow[r] = __expf(-sv * C1);
}

extern "C" void kernel_launch(void* const* d_in, const int* in_sizes, int n_in,
                              void* d_out, int out_size, void* d_ws, size_t ws_size,
                              hipStream_t stream) {
  const float* X    = (const float*)d_in[0];
  const float* A    = (const float*)d_in[1];
  const float* Aaff = (const float*)d_in[2];
  const float* baff = (const float*)d_in[3];
  float* out = (float*)d_out;

  char* w = (char*)d_ws;
  size_t off = 0;
  unsigned short* ATf = (unsigned short*)(w + off); off += (size_t)8 * 8 * 256 * 64 * 8 * 2; // 16 MiB
  unsigned short* Zf  = (unsigned short*)(w + off); off += (size_t)N_PTS * DIM * 2;          // 2 MiB
  float* erow = (float*)(w + off); off += (size_t)N_PTS * 4;
  float* Zf32 = (float*)(w + off); off += (size_t)N_PTS * DIM * 4;                           // 4 MiB
  unsigned short* Opart = (unsigned short*)(w + off); off += (size_t)8 * N_PTS * DIM * 2;    // 16 MiB
  (void)ws_size; (void)in_sizes; (void)n_in; (void)out_size;

  k_prep<<<dim3(64, 8, 8), 256, 0, stream>>>(A, ATf);
  k_init<<<512, 256, 0, stream>>>(X, Zf, erow);

  const float* zin = X;
  for (int t = 0; t < 8; ++t) {
    float* zout = (t == 7) ? out : Zf32;  // in-place safe after t=0
    k_flash<<<dim3(8, 64), 512, 0, stream>>>(
        Zf, erow, ATf + (size_t)t * (8 * 256 * 64 * 8), Aaff + (size_t)t * DIM * DIM, Opart);
    k_update<<<512, 256, 0, stream>>>(zin, Opart, baff + (size_t)t * DIM, zout, Zf, erow);
    zin = zout;
  }
}

// Round 13
// 365.759 us; speedup vs baseline: 1.0158x; 1.0022x over previous
//
#include <hip/hip_runtime.h>

// DiffeomorphicLearnerTorch, R17 (resubmit — MI355X container infra failure;
// kernel never ran). R17 = R16 (366.6us) + producer S-chain split.
// R16 post-mortem: halving barriers (10->5) was NEUTRAL -> barrier count
// exonerated. Per-SIMD audit: MFMA 17k cyc vs 92k wall, LDS ~5%, VALU ~5%,
// L2 ~17% — every THROUGHPUT pipe <=20% across six variants. Last resource
// never attacked: the producer's 16-deep dependent MFMA accumulation chain
// (dep latency ~100+cyc vs 32cyc issue => ~2k cyc/tile serial per P-wave;
// consumers have 4-way acc ILP, producer has 1).
// R17: (a) split S into Sa/Sb (even/odd ks, interleaved) — two independent
// 8-deep chains, summed in the exp arg; (b) pay the +16 VGPR by de-hoisting
// eI (reload per tile from erow, L1-hot broadcast) -> producer ~115 regs,
// (512,4) bound intact; (c) sZi staging via global_load_lds width=16
// (linear copy = supported wave-uniform+lane*16 pattern; kills the VGPR
// round-trip). Summation-order change only; threshold headroom 6x.
// Per step: Z += DT*(Z@Aaff^T + b + [ei*ej*exp(2*C1*Z@Z^T)]@A_t)
// Frag-linear layouts (verified R4/R5):
//   Zf  [128 jblk][16 ks][64 lane]x8 bf16
//   ATf [t][8 dblk][256 jb][64 lane]x8 bf16

#define N_PTS 4096
#define DIM   256
#define DT_C  0.125f
#define C1    (1.0f/512.0f)

typedef __bf16 bf16x8 __attribute__((ext_vector_type(8)));
typedef float  f32x16 __attribute__((ext_vector_type(16)));
typedef float  f32x4v __attribute__((ext_vector_type(4)));
typedef unsigned int   u32x4 __attribute__((ext_vector_type(4)));
typedef unsigned short u16x8 __attribute__((ext_vector_type(8)));

__device__ __forceinline__ unsigned short f2bf(float f) {
  unsigned int u = __builtin_bit_cast(unsigned int, f);
  u += 0x7fffu + ((u >> 16) & 1u);          // RNE
  return (unsigned short)(u >> 16);
}
__device__ __forceinline__ float bf2f(unsigned short s) {
  unsigned int u = ((unsigned int)s) << 16;
  return __builtin_bit_cast(float, u);
}

typedef __attribute__((address_space(1))) const unsigned int gas_u32;
typedef __attribute__((address_space(3))) unsigned int las_u32;
__device__ __forceinline__ void gload_lds16(const void* g, void* l) {
  __builtin_amdgcn_global_load_lds((gas_u32*)g, (las_u32*)l, 16, 0, 0);
}

// ---- ATf: A[t][4096][256] f32 -> frag-linear bf16 B-operand tiles ----
__global__ __launch_bounds__(256) void k_prep(const float* __restrict__ A,
                                              unsigned short* __restrict__ ATf) {
  __shared__ float sT[64][36];
  const int jgrp = blockIdx.x, ds = blockIdx.y, t = blockIdx.z;
  const int tid = threadIdx.x;
  const float* Ab = A + (size_t)t * N_PTS * DIM;
  {
    const int j_l = tid >> 2, dq = tid & 3;
    const float* src = Ab + (size_t)(jgrp * 64 + j_l) * DIM + ds * 32 + dq * 8;
    f32x4v v0 = *(const f32x4v*)src, v1 = *(const f32x4v*)(src + 4);
    *(f32x4v*)&sT[j_l][dq * 8] = v0;
    *(f32x4v*)&sT[j_l][dq * 8 + 4] = v1;
  }
  __syncthreads();
  const int jb_l = tid >> 6, l = tid & 63, l31 = l & 31, lhi = l >> 5;
  u16x8 o;
#pragma unroll
  for (int e = 0; e < 8; ++e) o[e] = f2bf(sT[jb_l * 16 + lhi * 8 + e][l31]);
  unsigned short* dst = ATf + (size_t)t * (8 * 256 * 64 * 8)
                      + ((size_t)(ds * 256 + jgrp * 4 + jb_l) * 64 + l) * 8;
  *(u16x8*)dst = o;
}

// ---- init: X -> Zf frags + erow ----
__global__ __launch_bounds__(256) void k_init(const float* __restrict__ X,
                                              unsigned short* __restrict__ Zf,
                                              float* __restrict__ erow) {
  const int tid = threadIdx.x;
  const int r = blockIdx.x * 8 + (tid >> 5), o = tid & 31;
  const size_t base = (size_t)r * DIM + o * 8;
  f32x4v z0 = *(const f32x4v*)(X + base), z1 = *(const f32x4v*)(X + base + 4);
  u16x8 zb; float s = 0.f;
#pragma unroll
  for (int i = 0; i < 4; ++i) { zb[i] = f2bf(z0[i]); zb[4 + i] = f2bf(z1[i]);
                                s += z0[i] * z0[i] + z1[i] * z1[i]; }
  *(u16x8*)(Zf + ((size_t)((r >> 5) * 16 + (o >> 1)) * 64 + (o & 1) * 32 + (r & 31)) * 8) = zb;
#pragma unroll
  for (int d = 16; d > 0; d >>= 1) s += __shfl_down(s, d, 32);
  if (o == 0) erow[r] = __expf(-s * C1);
}

// ---- fused flash (R6 structure + T5 setprio + 2-tile phases + split chains) ----
// grid (8 chunks, 64 i-tiles of 64 rows), 512 thr = 8 waves, 2 blocks/CU.
// waves 0-3 producer (ip=wid>>1, jh=wid&1): S^ = Zi(32) @ Zj(32)^T via TWO
//   interleaved 8-deep chains Sa/Sb; af from sZi (LDS), bv x16 from global;
//   eI reloaded per tile (L1-hot broadcast). P -> sP[n&3].
// waves 4-7 consumer cd: O(64i x 64d) += P @ A_t; bw x8 per tile;
//   + affine slice ksg=chunk*2+{0,1} (a-frags from sZi).
// Phases of 2 tiles; ONE barrier per phase (5 total incl. staging).
__global__ __launch_bounds__(512, 4) void k_flash(
    const unsigned short* __restrict__ Zf, const float* __restrict__ erow,
    const unsigned short* __restrict__ ATf_t,
    const float* __restrict__ Aaff_t,
    unsigned short* __restrict__ Opart) {
  __shared__ __align__(16) unsigned short sZi[64 * 256];   // 32KB frag-linear
  __shared__ __align__(16) unsigned short sP[4][64 * 64];  // 4 x 8KB swizzled

  const int tid = threadIdx.x, lane = tid & 63, wid = tid >> 6;
  const int l31 = lane & 31, lhi = lane >> 5;
  const int chunk = blockIdx.x;
  const int i0 = blockIdx.y * 64;
  const int ib = i0 >> 5;

  // stage sZi via global_load_lds (linear copy: wave-uniform base + lane*16)
  {
    const unsigned short* src = Zf + (size_t)ib * 8192;
#pragma unroll
    for (int p = 0; p < 4; ++p)
      gload_lds16(src + (size_t)(p * 512 + tid) * 8,
                  sZi + (size_t)(p * 512 + tid) * 8);
  }
  __syncthreads();

  if (wid < 4) {
    // ================= producer =================
    const int ip = wid >> 1, jh = wid & 1;
    const float* eIb = erow + i0 + ip * 32 + 4 * lhi;   // + (c&3) + 8*(c>>2)

    for (int ph = 0; ph < 4; ++ph) {
#pragma unroll
      for (int h = 0; h < 2; ++h) {
        const int n = ph * 2 + h;
        // hoist the 16 b-frags for this tile
        u32x4 bv[16];
        {
          const unsigned short* bp =
              Zf + ((size_t)(chunk * 16 + n * 2 + jh) * 16 * 64 + lane) * 8;
#pragma unroll
          for (int ks = 0; ks < 16; ++ks) bv[ks] = *(const u32x4*)(bp + ks * 512);
        }
        // split chains: Sa (even ks), Sb (odd ks) — two independent 8-deep
        // dependent chains interleaved on the MFMA pipe.
        f32x16 Sa, Sb;
#pragma unroll
        for (int i = 0; i < 16; ++i) { Sa[i] = 0.f; Sb[i] = 0.f; }
        __builtin_amdgcn_s_setprio(1);
#pragma unroll
        for (int ks = 0; ks < 16; ks += 2) {
          bf16x8 a0 = *(const bf16x8*)(sZi + ((size_t)(ip * 16 + ks) * 64 + lane) * 8);
          bf16x8 a1 = *(const bf16x8*)(sZi + ((size_t)(ip * 16 + ks + 1) * 64 + lane) * 8);
          Sa = __builtin_amdgcn_mfma_f32_32x32x16_bf16(
              a0, __builtin_bit_cast(bf16x8, bv[ks + 0]), Sa, 0, 0, 0);
          Sb = __builtin_amdgcn_mfma_f32_32x32x16_bf16(
              a1, __builtin_bit_cast(bf16x8, bv[ks + 1]), Sb, 0, 0, 0);
        }
        __builtin_amdgcn_s_setprio(0);
        const float ej = erow[chunk * 512 + n * 64 + jh * 32 + l31];
        unsigned short* pb = sP[n & 3];
        const int blk = jh * 4 + (l31 >> 3), cl = l31 & 7;
#pragma unroll
        for (int c = 0; c < 16; ++c) {
          const int row = ip * 32 + 4 * lhi + (c & 3) + 8 * (c >> 2);
          const float eIc = eIb[(c & 3) + 8 * (c >> 2)];   // L1-hot broadcast
          pb[row * 64 + ((blk ^ (row & 7)) * 8) + cl] =
              f2bf(eIc * ej * __expf(2.f * C1 * (Sa[c] + Sb[c])));
        }
      }
      __syncthreads();   // publish tiles 2p, 2p+1
    }
  } else {
    // ================= consumer =================
    const int cd = wid - 4;
    f32x16 O[2][2];
#pragma unroll
    for (int rs = 0; rs < 2; ++rs)
#pragma unroll
      for (int ct = 0; ct < 2; ++ct)
#pragma unroll
        for (int i = 0; i < 16; ++i) O[rs][ct][i] = 0.f;

    // affine slice (unscaled): ksg = chunk*2 + {0,1}; a-frags from sZi
#pragma unroll
    for (int q = 0; q < 2; ++q) {
      const int ksg = chunk * 2 + q;
      bf16x8 a[2];
#pragma unroll
      for (int rs = 0; rs < 2; ++rs)
        a[rs] = *(const bf16x8*)(sZi + ((size_t)(rs * 16 + ksg) * 64 + lane) * 8);
#pragma unroll
      for (int ct = 0; ct < 2; ++ct) {
        const int d = cd * 64 + ct * 32 + l31;
        const float* bp = Aaff_t + (size_t)d * DIM + ksg * 16 + lhi * 8;
        f32x4v f0 = *(const f32x4v*)bp, f1 = *(const f32x4v*)(bp + 4);
        u16x8 tb;
#pragma unroll
        for (int i = 0; i < 4; ++i) { tb[i] = f2bf(f0[i]); tb[4 + i] = f2bf(f1[i]); }
        bf16x8 bv = __builtin_bit_cast(bf16x8, tb);
#pragma unroll
        for (int rs = 0; rs < 2; ++rs)
          O[rs][ct] = __builtin_amdgcn_mfma_f32_32x32x16_bf16(a[rs], bv, O[rs][ct], 0, 0, 0);
      }
    }

    for (int ph = 0; ph < 4; ++ph) {
      __syncthreads();   // tiles 2p, 2p+1 published
#pragma unroll
      for (int h = 0; h < 2; ++h) {
        const int m = ph * 2 + h;
        // hoist the 8 ATf b-frags for this tile
        u32x4 bw[8];
#pragma unroll
        for (int ks = 0; ks < 4; ++ks)
#pragma unroll
          for (int ct = 0; ct < 2; ++ct)
            bw[ks * 2 + ct] = *(const u32x4*)(ATf_t +
                ((size_t)((cd * 2 + ct) * 256 + chunk * 32 + m * 4 + ks) * 64 + lane) * 8);
        const unsigned short* pb = sP[m & 3];
#pragma unroll
        for (int ks = 0; ks < 4; ++ks) {
          bf16x8 a[2];
          const int blk = ks * 2 + lhi;
#pragma unroll
          for (int rs = 0; rs < 2; ++rs) {
            const int row = rs * 32 + l31;
            a[rs] = *(const bf16x8*)&pb[row * 64 + ((blk ^ (row & 7)) * 8)];
          }
          __builtin_amdgcn_s_setprio(1);
#pragma unroll
          for (int rs = 0; rs < 2; ++rs)
#pragma unroll
            for (int ct = 0; ct < 2; ++ct)
              O[rs][ct] = __builtin_amdgcn_mfma_f32_32x32x16_bf16(
                  a[rs], __builtin_bit_cast(bf16x8, bw[ks * 2 + ct]), O[rs][ct], 0, 0, 0);
          __builtin_amdgcn_s_setprio(0);
        }
      }
    }

    // epilogue -> Opart[chunk] bf16 (P already carries ei*ej)
    unsigned short* ob = Opart + (size_t)chunk * N_PTS * DIM + (size_t)cd * 64 + l31;
#pragma unroll
    for (int rs = 0; rs < 2; ++rs)
#pragma unroll
      for (int c = 0; c < 16; ++c) {
        const int row = i0 + rs * 32 + 4 * lhi + (c & 3) + 8 * (c >> 2);
        ob[(size_t)row * DIM]      = f2bf(O[rs][0][c]);
        ob[(size_t)row * DIM + 32] = f2bf(O[rs][1][c]);
      }
  }
}

// ---- update: Z += DT*(sum partials + baff); emit Zf frags + erow ----
__global__ __launch_bounds__(256) void k_update(const float* __restrict__ Zin,
                                                const unsigned short* __restrict__ Opart,
                                                const float* __restrict__ baff_t,
                                                float* __restrict__ Zout,
                                                unsigned short* __restrict__ Zf,
                                                float* __restrict__ erow) {
  const int tid = threadIdx.x;
  const int r = blockIdx.x * 8 + (tid >> 5), o = tid & 31;
  const size_t base = (size_t)r * DIM + o * 8;
  f32x4v z0 = *(const f32x4v*)(Zin + base), z1 = *(const f32x4v*)(Zin + base + 4);
  f32x4v s0 = *(const f32x4v*)(baff_t + o * 8), s1 = *(const f32x4v*)(baff_t + o * 8 + 4);
#pragma unroll
  for (int c = 0; c < 8; ++c) {
    u16x8 p = *(const u16x8*)(Opart + (size_t)c * N_PTS * DIM + base);
#pragma unroll
    for (int i = 0; i < 4; ++i) { s0[i] += bf2f(p[i]); s1[i] += bf2f(p[4 + i]); }
  }
  u16x8 zb; float sv = 0.f;
#pragma unroll
  for (int i = 0; i < 4; ++i) {
    z0[i] += DT_C * s0[i]; z1[i] += DT_C * s1[i];
    zb[i] = f2bf(z0[i]); zb[4 + i] = f2bf(z1[i]);
    sv += z0[i] * z0[i] + z1[i] * z1[i];
  }
  *(f32x4v*)(Zout + base) = z0;
  *(f32x4v*)(Zout + base + 4) = z1;
  *(u16x8*)(Zf + ((size_t)((r >> 5) * 16 + (o >> 1)) * 64 + (o & 1) * 32 + (r & 31)) * 8) = zb;
#pragma unroll
  for (int d = 16; d > 0; d >>= 1) sv += __shfl_down(sv, d, 32);
  if (o == 0) erow[r] = __expf(-sv * C1);
}

extern "C" void kernel_launch(void* const* d_in, const int* in_sizes, int n_in,
                              void* d_out, int out_size, void* d_ws, size_t ws_size,
                              hipStream_t stream) {
  const float* X    = (const float*)d_in[0];
  const float* A    = (const float*)d_in[1];
  const float* Aaff = (const float*)d_in[2];
  const float* baff = (const float*)d_in[3];
  float* out = (float*)d_out;

  char* w = (char*)d_ws;
  size_t off = 0;
  unsigned short* ATf = (unsigned short*)(w + off); off += (size_t)8 * 8 * 256 * 64 * 8 * 2; // 16 MiB
  unsigned short* Zf  = (unsigned short*)(w + off); off += (size_t)N_PTS * DIM * 2;          // 2 MiB
  float* erow = (float*)(w + off); off += (size_t)N_PTS * 4;
  float* Zf32 = (float*)(w + off); off += (size_t)N_PTS * DIM * 4;                           // 4 MiB
  unsigned short* Opart = (unsigned short*)(w + off); off += (size_t)8 * N_PTS * DIM * 2;    // 16 MiB
  (void)ws_size; (void)in_sizes; (void)n_in; (void)out_size;

  k_prep<<<dim3(64, 8, 8), 256, 0, stream>>>(A, ATf);
  k_init<<<512, 256, 0, stream>>>(X, Zf, erow);

  const float* zin = X;
  for (int t = 0; t < 8; ++t) {
    float* zout = (t == 7) ? out : Zf32;  // in-place safe after t=0
    k_flash<<<dim3(8, 64), 512, 0, stream>>>(
        Zf, erow, ATf + (size_t)t * (8 * 256 * 64 * 8), Aaff + (size_t)t * DIM * DIM, Opart);
    k_update<<<512, 256, 0, stream>>>(zin, Opart, baff + (size_t)t * DIM, zout, Zf, erow);
    zin = zout;
  }
}

// Round 14
// 361.136 us; speedup vs baseline: 1.0288x; 1.0128x over previous
//
#include <hip/hip_runtime.h>

// DiffeomorphicLearnerTorch, R18 — af-resident + Zj-through-LDS (the untested
// third corner of the R5/R6 trade-off).
// R17 post-mortem: chain split NEUTRAL -> dep-chain ILP exonerated. Cleared
// so far at ~366us: VALU count, L2 operand path, staging depth, barrier
// count, chain ILP, occupancy regime. Last untested combination: R5 had
// af[16] in regs but bv fell into 2-deep L2 batches (exposed latency); R6
// moved af to LDS to hoist bv 16-deep, putting 16 L2 loads on every
// producer tile's critical path. R18: af resident AND bv from LDS —
// producer inner loop = pure reg-MFMA fed by ~120cyc ds_reads; Zj streamed
// via producer-staged double-buffered global_load_lds (32KB/tile, 8x16B
// per producer thread, async, consumed next tile).
// sZi deleted: af[16] read from global ONCE (producers), affine a-frags
// from global ONCE (consumers). LDS = sP[2] 16KB + sZj[2] 64KB = 80KB ->
// 2 blocks/CU kept. Single S chain (R17 split neutral; saves 16 regs):
// producer ~110 regs, consumer ~111, under the (512,4) 128 cap.
// Barrier cadence = R14's verified pattern (10 per role).
// Math identical to R6/R14 (verified, absmax 0.015625).
// Per step: Z += DT*(Z@Aaff^T + b + [ei*ej*exp(2*C1*Z@Z^T)]@A_t)
// Frag-linear layouts (verified R4/R5):
//   Zf  [128 jblk][16 ks][64 lane]x8 bf16
//   ATf [t][8 dblk][256 jb][64 lane]x8 bf16

#define N_PTS 4096
#define DIM   256
#define DT_C  0.125f
#define C1    (1.0f/512.0f)

typedef __bf16 bf16x8 __attribute__((ext_vector_type(8)));
typedef float  f32x16 __attribute__((ext_vector_type(16)));
typedef float  f32x4v __attribute__((ext_vector_type(4)));
typedef unsigned int   u32x4 __attribute__((ext_vector_type(4)));
typedef unsigned short u16x8 __attribute__((ext_vector_type(8)));

__device__ __forceinline__ unsigned short f2bf(float f) {
  unsigned int u = __builtin_bit_cast(unsigned int, f);
  u += 0x7fffu + ((u >> 16) & 1u);          // RNE
  return (unsigned short)(u >> 16);
}
__device__ __forceinline__ float bf2f(unsigned short s) {
  unsigned int u = ((unsigned int)s) << 16;
  return __builtin_bit_cast(float, u);
}

typedef __attribute__((address_space(1))) const unsigned int gas_u32;
typedef __attribute__((address_space(3))) unsigned int las_u32;
__device__ __forceinline__ void gload_lds16(const void* g, void* l) {
  __builtin_amdgcn_global_load_lds((gas_u32*)g, (las_u32*)l, 16, 0, 0);
}

// ---- ATf: A[t][4096][256] f32 -> frag-linear bf16 B-operand tiles ----
__global__ __launch_bounds__(256) void k_prep(const float* __restrict__ A,
                                              unsigned short* __restrict__ ATf) {
  __shared__ float sT[64][36];
  const int jgrp = blockIdx.x, ds = blockIdx.y, t = blockIdx.z;
  const int tid = threadIdx.x;
  const float* Ab = A + (size_t)t * N_PTS * DIM;
  {
    const int j_l = tid >> 2, dq = tid & 3;
    const float* src = Ab + (size_t)(jgrp * 64 + j_l) * DIM + ds * 32 + dq * 8;
    f32x4v v0 = *(const f32x4v*)src, v1 = *(const f32x4v*)(src + 4);
    *(f32x4v*)&sT[j_l][dq * 8] = v0;
    *(f32x4v*)&sT[j_l][dq * 8 + 4] = v1;
  }
  __syncthreads();
  const int jb_l = tid >> 6, l = tid & 63, l31 = l & 31, lhi = l >> 5;
  u16x8 o;
#pragma unroll
  for (int e = 0; e < 8; ++e) o[e] = f2bf(sT[jb_l * 16 + lhi * 8 + e][l31]);
  unsigned short* dst = ATf + (size_t)t * (8 * 256 * 64 * 8)
                      + ((size_t)(ds * 256 + jgrp * 4 + jb_l) * 64 + l) * 8;
  *(u16x8*)dst = o;
}

// ---- init: X -> Zf frags + erow ----
__global__ __launch_bounds__(256) void k_init(const float* __restrict__ X,
                                              unsigned short* __restrict__ Zf,
                                              float* __restrict__ erow) {
  const int tid = threadIdx.x;
  const int r = blockIdx.x * 8 + (tid >> 5), o = tid & 31;
  const size_t base = (size_t)r * DIM + o * 8;
  f32x4v z0 = *(const f32x4v*)(X + base), z1 = *(const f32x4v*)(X + base + 4);
  u16x8 zb; float s = 0.f;
#pragma unroll
  for (int i = 0; i < 4; ++i) { zb[i] = f2bf(z0[i]); zb[4 + i] = f2bf(z1[i]);
                                s += z0[i] * z0[i] + z1[i] * z1[i]; }
  *(u16x8*)(Zf + ((size_t)((r >> 5) * 16 + (o >> 1)) * 64 + (o & 1) * 32 + (r & 31)) * 8) = zb;
#pragma unroll
  for (int d = 16; d > 0; d >>= 1) s += __shfl_down(s, d, 32);
  if (o == 0) erow[r] = __expf(-s * C1);
}

// ---- fused flash (R18: af-resident producer, Zj double-buffered in LDS) ----
// grid (8 chunks, 64 i-tiles of 64 rows), 512 thr = 8 waves, 2 blocks/CU.
// waves 0-3 producer (ip=wid>>1, jh=wid&1): S = Zi(32) @ Zj(32)^T;
//   af[16] RESIDENT (global, once); bv from sZj[cur] (ds_read); producers
//   stage sZj[(n+1)&1] via 8x gload_lds16/thread. P -> sP[n&1].
// waves 4-7 consumer cd: O(64i x 64d) += P @ A_t; bw x8 from global/tile;
//   + affine slice ksg=chunk*2+{0,1} (a-frags from global, once).
__global__ __launch_bounds__(512, 4) void k_flash(
    const unsigned short* __restrict__ Zf, const float* __restrict__ erow,
    const unsigned short* __restrict__ ATf_t,
    const float* __restrict__ Aaff_t,
    unsigned short* __restrict__ Opart) {
  __shared__ __align__(16) unsigned short sP[2][64 * 64];       // 2 x 8KB swizzled
  __shared__ __align__(16) unsigned short sZj[2][2 * 16 * 64 * 8]; // 2 x 32KB

  const int tid = threadIdx.x, lane = tid & 63, wid = tid >> 6;
  const int l31 = lane & 31, lhi = lane >> 5;
  const int chunk = blockIdx.x;
  const int i0 = blockIdx.y * 64;
  const int ib = i0 >> 5;
  const unsigned short* zib = Zf + (size_t)ib * 8192;           // 64 i-rows, frag-linear
  const unsigned short* zjs = Zf + (size_t)(chunk * 16) * 8192; // chunk j-region

  if (wid < 4) {
    // ================= producer =================
    const int ip = wid >> 1, jh = wid & 1;

    // stage tile 0 (32KB over 256 producer threads: 8 x 16B each)
#pragma unroll
    for (int p = 0; p < 8; ++p)
      gload_lds16(zjs + (size_t)(p * 256 + tid) * 8,
                  sZj[0] + (size_t)(p * 256 + tid) * 8);

    // af[16] resident: wave's 32 i-rows x K=256, from global (once)
    u32x4 af[16];
#pragma unroll
    for (int ks = 0; ks < 16; ++ks)
      af[ks] = *(const u32x4*)(zib + ((size_t)(ip * 16 + ks) * 64 + lane) * 8);

    const float* eIb = erow + i0 + ip * 32 + 4 * lhi;   // + (c&3) + 8*(c>>2)
    __syncthreads();   // stage barrier: sZj[0] ready (vmcnt drained)

    for (int n = 0; n < 8; ++n) {
      const int cur = n & 1;
      // stage tile n+1 into the other buffer (async; drained at barrier)
      if (n < 7) {
        const unsigned short* src = zjs + (size_t)(n + 1) * 16384;
#pragma unroll
        for (int p = 0; p < 8; ++p)
          gload_lds16(src + (size_t)(p * 256 + tid) * 8,
                      sZj[cur ^ 1] + (size_t)(p * 256 + tid) * 8);
      }
      // S chain: af (regs) x bv (LDS ds_read_b128, ~120cyc, prefetchable)
      f32x16 S;
#pragma unroll
      for (int i = 0; i < 16; ++i) S[i] = 0.f;
      __builtin_amdgcn_s_setprio(1);
#pragma unroll
      for (int ks = 0; ks < 16; ++ks) {
        bf16x8 bv = *(const bf16x8*)(sZj[cur] + ((size_t)(jh * 16 + ks) * 64 + lane) * 8);
        S = __builtin_amdgcn_mfma_f32_32x32x16_bf16(
            __builtin_bit_cast(bf16x8, af[ks]), bv, S, 0, 0, 0);
      }
      __builtin_amdgcn_s_setprio(0);
      const float ej = erow[chunk * 512 + n * 64 + jh * 32 + l31];
      unsigned short* pb = sP[n & 1];
      const int blk = jh * 4 + (l31 >> 3), cl = l31 & 7;
#pragma unroll
      for (int c = 0; c < 16; ++c) {
        const int row = ip * 32 + 4 * lhi + (c & 3) + 8 * (c >> 2);
        const float eIc = eIb[(c & 3) + 8 * (c >> 2)];   // L1-hot broadcast
        pb[row * 64 + ((blk ^ (row & 7)) * 8) + cl] =
            f2bf(eIc * ej * __expf(2.f * C1 * S[c]));
      }
      __syncthreads();
    }
    __syncthreads();   // match consumer's final barrier
  } else {
    // ================= consumer =================
    const int cd = wid - 4;
    f32x16 O[2][2];
#pragma unroll
    for (int rs = 0; rs < 2; ++rs)
#pragma unroll
      for (int ct = 0; ct < 2; ++ct)
#pragma unroll
        for (int i = 0; i < 16; ++i) O[rs][ct][i] = 0.f;

    // affine slice (unscaled): ksg = chunk*2+{0,1}; a-frags from GLOBAL
#pragma unroll
    for (int q = 0; q < 2; ++q) {
      const int ksg = chunk * 2 + q;
      bf16x8 a[2];
#pragma unroll
      for (int rs = 0; rs < 2; ++rs)
        a[rs] = *(const bf16x8*)(zib + ((size_t)(rs * 16 + ksg) * 64 + lane) * 8);
#pragma unroll
      for (int ct = 0; ct < 2; ++ct) {
        const int d = cd * 64 + ct * 32 + l31;
        const float* bp = Aaff_t + (size_t)d * DIM + ksg * 16 + lhi * 8;
        f32x4v f0 = *(const f32x4v*)bp, f1 = *(const f32x4v*)(bp + 4);
        u16x8 tb;
#pragma unroll
        for (int i = 0; i < 4; ++i) { tb[i] = f2bf(f0[i]); tb[4 + i] = f2bf(f1[i]); }
        bf16x8 bv = __builtin_bit_cast(bf16x8, tb);
#pragma unroll
        for (int rs = 0; rs < 2; ++rs)
          O[rs][ct] = __builtin_amdgcn_mfma_f32_32x32x16_bf16(a[rs], bv, O[rs][ct], 0, 0, 0);
      }
    }
    __syncthreads();   // stage barrier (producers staged sZj[0])
    __syncthreads();   // barrier 1 (producer finished tile 0)

    for (int n = 1; n <= 8; ++n) {
      const int m = n - 1;
      // hoist the 8 ATf b-frags (R14 placement)
      u32x4 bw[8];
#pragma unroll
      for (int ks = 0; ks < 4; ++ks)
#pragma unroll
        for (int ct = 0; ct < 2; ++ct)
          bw[ks * 2 + ct] = *(const u32x4*)(ATf_t +
              ((size_t)((cd * 2 + ct) * 256 + chunk * 32 + m * 4 + ks) * 64 + lane) * 8);
      const unsigned short* pb = sP[m & 1];
#pragma unroll
      for (int ks = 0; ks < 4; ++ks) {
        bf16x8 a[2];
        const int blk = ks * 2 + lhi;
#pragma unroll
        for (int rs = 0; rs < 2; ++rs) {
          const int row = rs * 32 + l31;
          a[rs] = *(const bf16x8*)&pb[row * 64 + ((blk ^ (row & 7)) * 8)];
        }
        __builtin_amdgcn_s_setprio(1);
#pragma unroll
        for (int rs = 0; rs < 2; ++rs)
#pragma unroll
          for (int ct = 0; ct < 2; ++ct)
            O[rs][ct] = __builtin_amdgcn_mfma_f32_32x32x16_bf16(
                a[rs], __builtin_bit_cast(bf16x8, bw[ks * 2 + ct]), O[rs][ct], 0, 0, 0);
        __builtin_amdgcn_s_setprio(0);
      }
      __syncthreads();
    }

    // epilogue -> Opart[chunk] bf16 (P already carries ei*ej)
    unsigned short* ob = Opart + (size_t)chunk * N_PTS * DIM + (size_t)cd * 64 + l31;
#pragma unroll
    for (int rs = 0; rs < 2; ++rs)
#pragma unroll
      for (int c = 0; c < 16; ++c) {
        const int row = i0 + rs * 32 + 4 * lhi + (c & 3) + 8 * (c >> 2);
        ob[(size_t)row * DIM]      = f2bf(O[rs][0][c]);
        ob[(size_t)row * DIM + 32] = f2bf(O[rs][1][c]);
      }
  }
}

// ---- update: Z += DT*(sum partials + baff); emit Zf frags + erow ----
__global__ __launch_bounds__(256) void k_update(const float* __restrict__ Zin,
                                                const unsigned short* __restrict__ Opart,
                                                const float* __restrict__ baff_t,
                                                float* __restrict__ Zout,
                                                unsigned short* __restrict__ Zf,
                                                float* __restrict__ erow) {
  const int tid = threadIdx.x;
  const int r = blockIdx.x * 8 + (tid >> 5), o = tid & 31;
  const size_t base = (size_t)r * DIM + o * 8;
  f32x4v z0 = *(const f32x4v*)(Zin + base), z1 = *(const f32x4v*)(Zin + base + 4);
  f32x4v s0 = *(const f32x4v*)(baff_t + o * 8), s1 = *(const f32x4v*)(baff_t + o * 8 + 4);
#pragma unroll
  for (int c = 0; c < 8; ++c) {
    u16x8 p = *(const u16x8*)(Opart + (size_t)c * N_PTS * DIM + base);
#pragma unroll
    for (int i = 0; i < 4; ++i) { s0[i] += bf2f(p[i]); s1[i] += bf2f(p[4 + i]); }
  }
  u16x8 zb; float sv = 0.f;
#pragma unroll
  for (int i = 0; i < 4; ++i) {
    z0[i] += DT_C * s0[i]; z1[i] += DT_C * s1[i];
    zb[i] = f2bf(z0[i]); zb[4 + i] = f2bf(z1[i]);
    sv += z0[i] * z0[i] + z1[i] * z1[i];
  }
  *(f32x4v*)(Zout + base) = z0;
  *(f32x4v*)(Zout + base + 4) = z1;
  *(u16x8*)(Zf + ((size_t)((r >> 5) * 16 + (o >> 1)) * 64 + (o & 1) * 32 + (r & 31)) * 8) = zb;
#pragma unroll
  for (int d = 16; d > 0; d >>= 1) sv += __shfl_down(sv, d, 32);
  if (o == 0) erow[r] = __expf(-sv * C1);
}

extern "C" void kernel_launch(void* const* d_in, const int* in_sizes, int n_in,
                              void* d_out, int out_size, void* d_ws, size_t ws_size,
                              hipStream_t stream) {
  const float* X    = (const float*)d_in[0];
  const float* A    = (const float*)d_in[1];
  const float* Aaff = (const float*)d_in[2];
  const float* baff = (const float*)d_in[3];
  float* out = (float*)d_out;

  char* w = (char*)d_ws;
  size_t off = 0;
  unsigned short* ATf = (unsigned short*)(w + off); off += (size_t)8 * 8 * 256 * 64 * 8 * 2; // 16 MiB
  unsigned short* Zf  = (unsigned short*)(w + off); off += (size_t)N_PTS * DIM * 2;          // 2 MiB
  float* erow = (float*)(w + off); off += (size_t)N_PTS * 4;
  float* Zf32 = (float*)(w + off); off += (size_t)N_PTS * DIM * 4;                           // 4 MiB
  unsigned short* Opart = (unsigned short*)(w + off); off += (size_t)8 * N_PTS * DIM * 2;    // 16 MiB
  (void)ws_size; (void)in_sizes; (void)n_in; (void)out_size;

  k_prep<<<dim3(64, 8, 8), 256, 0, stream>>>(A, ATf);
  k_init<<<512, 256, 0, stream>>>(X, Zf, erow);

  const float* zin = X;
  for (int t = 0; t < 8; ++t) {
    float* zout = (t == 7) ? out : Zf32;  // in-place safe after t=0
    k_flash<<<dim3(8, 64), 512, 0, stream>>>(
        Zf, erow, ATf + (size_t)t * (8 * 256 * 64 * 8), Aaff + (size_t)t * DIM * DIM, Opart);
    k_update<<<512, 256, 0, stream>>>(zin, Opart, baff + (size_t)t * DIM, zout, Zf, erow);
    zin = zout;
  }
}